// Round 4
// baseline (8848.103 us; speedup 1.0000x reference)
//
#include <hip/hip_runtime.h>

#define D_MODEL 768
#define NH 24
#define HP 64
#define NSTATE 64
#define DIN 1536
#define CONV_DIM 1664
#define DPROJ 3224
#define TLEN 4161
#define IMG 4096
#define NCHUNK 33
#define CHUNK 128
#define TPAD (NCHUNK*CHUNK)
#define KCONV 19200

__device__ __forceinline__ float softplusf(float x) { return x > 20.f ? x : log1pf(expf(x)); }
__device__ __forceinline__ float siluf(float x) { return x / (1.f + expf(-x)); }

typedef __attribute__((ext_vector_type(8))) short short8v;
typedef __attribute__((ext_vector_type(4))) float ffrag;

// split fp32 -> (hi, lo) bf16 pair, both round-to-nearest-even
__device__ __forceinline__ void splitf(float x, short& h, short& l) {
  unsigned u = __float_as_uint(x);
  unsigned r = (u + 0x7FFFu + ((u >> 16) & 1u)) & 0xFFFF0000u;
  h = (short)(r >> 16);
  float hf = __uint_as_float(r);
  float lof = x - hf;
  unsigned u2 = __float_as_uint(lof);
  unsigned r2 = u2 + 0x7FFFu + ((u2 >> 16) & 1u);
  l = (short)(r2 >> 16);
}

// builtin (not inline asm): compiler handles MFMA hazard s_nops + scheduling
__device__ __forceinline__ void mfma_bf16(ffrag& c, short8v a, short8v b) {
  c = __builtin_amdgcn_mfma_f32_16x16x32_bf16(a, b, c, 0, 0, 0);
}

// ---------------- embed / build x ----------------
__global__ void e8_kernel(const float* __restrict__ im8, const float* __restrict__ w,
                          const float* __restrict__ b, float* __restrict__ e8) {
  int gid = blockIdx.x * blockDim.x + threadIdx.x;
  if (gid >= 64 * D_MODEL) return;
  int j = gid / D_MODEL, d = gid % D_MODEL;
  float acc = b[d];
  for (int c = 0; c < 3; c++) acc += im8[j * 3 + c] * w[d * 3 + c];
  e8[gid] = acc;
}

__global__ void build_x_kernel(const float* __restrict__ e8, const float* __restrict__ s0,
                               const float* __restrict__ suffix, float* __restrict__ out) {
  for (int gid = blockIdx.x * blockDim.x + threadIdx.x; gid < TLEN * D_MODEL;
       gid += gridDim.x * blockDim.x) {
    int t = gid / D_MODEL, d = gid % D_MODEL;
    float v;
    if (t == 0) v = s0[d];
    else if (t < 65) v = e8[(t - 1) * D_MODEL + d];
    else {
      int i = t - 65;
      int r = i >> 6, c = i & 63;
      v = e8[((r >> 3) * 8 + (c >> 3)) * D_MODEL + d] + suffix[(size_t)i * D_MODEL + d];
    }
    out[gid] = v;
  }
}

// ---------------- layer norm (cols = 768), optional split-bf16 output ----------------
__global__ __launch_bounds__(256) void ln_kernel(const float* __restrict__ in,
                                                 const float* __restrict__ w, const float* __restrict__ b,
                                                 float* __restrict__ outf,
                                                 short* __restrict__ oh, short* __restrict__ ol,
                                                 int rows) {
  int r = blockIdx.x;
  if (r >= rows) return;
  const float* row = in + (size_t)r * D_MODEL;
  __shared__ float red[256];
  int tid = threadIdx.x;
  float v0 = row[tid], v1 = row[tid + 256], v2 = row[tid + 512];
  red[tid] = v0 + v1 + v2;
  __syncthreads();
  for (int o = 128; o; o >>= 1) { if (tid < o) red[tid] += red[tid + o]; __syncthreads(); }
  float mu = red[0] / (float)D_MODEL;
  __syncthreads();
  float d0 = v0 - mu, d1 = v1 - mu, d2 = v2 - mu;
  red[tid] = d0 * d0 + d1 * d1 + d2 * d2;
  __syncthreads();
  for (int o = 128; o; o >>= 1) { if (tid < o) red[tid] += red[tid + o]; __syncthreads(); }
  float inv = rsqrtf(red[0] / (float)D_MODEL + 1e-5f);
  float r0 = d0 * inv * w[tid] + b[tid];
  float r1 = d1 * inv * w[tid + 256] + b[tid + 256];
  float r2 = d2 * inv * w[tid + 512] + b[tid + 512];
  if (oh) {
    size_t base = (size_t)r * D_MODEL;
    short h, l;
    splitf(r0, h, l); oh[base + tid] = h; ol[base + tid] = l;
    splitf(r1, h, l); oh[base + tid + 256] = h; ol[base + tid + 256] = l;
    splitf(r2, h, l); oh[base + tid + 512] = h; ol[base + tid + 512] = l;
  } else {
    float* orow = outf + (size_t)r * D_MODEL;
    orow[tid] = r0; orow[tid + 256] = r1; orow[tid + 512] = r2;
  }
}

// ---------------- weight split kernels ----------------
__global__ void split_mat_kernel(const float* __restrict__ src, short* __restrict__ hi,
                                 short* __restrict__ lo, int n) {
  for (int i = blockIdx.x * blockDim.x + threadIdx.x; i < n; i += gridDim.x * blockDim.x) {
    short h, l; splitf(src[i], h, l);
    hi[i] = h; lo[i] = l;
  }
}

// conv2d_w [tap][ic][oc] -> Wt[oc][tap*768+ic] split bf16 (transposed, 32x32 tiles)
__global__ __launch_bounds__(256) void split_convw_kernel(const float* __restrict__ W,
                                                          short* __restrict__ hi,
                                                          short* __restrict__ lo) {
  __shared__ float t[32][33];
  int tap = blockIdx.x;
  int ic0 = blockIdx.y * 32, oc0 = blockIdx.z * 32;
  int tid = threadIdx.x;
  #pragma unroll
  for (int e = 0; e < 4; e++) {
    int idx = tid + e * 256;
    int r = idx >> 5, c = idx & 31;   // r=ic, c=oc
    t[r][c] = W[((size_t)tap * 768 + ic0 + r) * 768 + oc0 + c];
  }
  __syncthreads();
  #pragma unroll
  for (int e = 0; e < 4; e++) {
    int idx = tid + e * 256;
    int r = idx & 31, c = idx >> 5;   // r=ic (fast, coalesced store), c=oc
    short h, l; splitf(t[r][c], h, l);
    size_t o = (size_t)(oc0 + c) * KCONV + (size_t)tap * 768 + ic0 + r;
    hi[o] = h; lo[o] = l;
  }
}

// ---------------- split-bf16 MFMA GEMM: C(M,N) = A(M,K) * B(N,K)^T ----------------
// Effective-fp32 via A,B ~ hi+lo bf16 pairs: C += Ah*Bh + Ah*Bl + Al*Bh (fp32 acc).
// CONV=1: implicit-GEMM conv2d 5x5 SAME; A gathered from 4096-px image (768 ch),
// B = Wt[oc][tap*768+ic] (ldb=19200); blockIdx.z selects 5-tap group -> partial C.
template<int CONV>
__global__ __launch_bounds__(256, 2) void mm_bf16(
    const short* __restrict__ Ah, const short* __restrict__ Al,
    const short* __restrict__ Bh, const short* __restrict__ Bl,
    float* __restrict__ C, float* __restrict__ Cpart,
    int M, int N, int K, int ldb) {
  __shared__ __align__(16) short AsH[128 * 64];
  __shared__ __align__(16) short AsL[128 * 64];
  __shared__ __align__(16) short BsH[128 * 64];
  __shared__ __align__(16) short BsL[128 * 64];
  const int bm = blockIdx.x * 128;
  const int bn = blockIdx.y * 128;
  const int tid = threadIdx.x;
  const int lane = tid & 63;
  const int wid = tid >> 6;
  const int wm = (wid >> 1) * 64, wn = (wid & 1) * 64;
  const int lm = lane & 15, lk = lane >> 4;
  const int tap0 = CONV ? blockIdx.z * 5 : 0;
  const int nsteps = CONV ? 5 * 12 : K / 64;
  float* Cout = C;
  if (CONV && blockIdx.z > 0) Cout = Cpart + (size_t)(blockIdx.z - 1) * IMG * D_MODEL;
  const short8v ZV = {0, 0, 0, 0, 0, 0, 0, 0};

  short8v sAh[4], sAl[4], sBh[4], sBl[4];
  int s_row[4], s_kc[4];
  #pragma unroll
  for (int e = 0; e < 4; e++) { int id = tid + e * 256; s_row[e] = id >> 3; s_kc[e] = id & 7; }

  auto stage = [&](int step) {
    int k0, tap = 0;
    if (CONV) { tap = tap0 + step / 12; k0 = (step % 12) * 64; }
    else k0 = step * 64;
    #pragma unroll
    for (int e = 0; e < 4; e++) {
      int row = s_row[e], kc = s_kc[e];
      bool av; size_t aoff;
      if (CONV) {
        int px = bm + row;
        int r = (px >> 6) + tap / 5 - 2;
        int c = (px & 63) + tap % 5 - 2;
        av = (r >= 0 && r < 64 && c >= 0 && c < 64);
        aoff = (size_t)(r * 64 + c) * 768 + k0 + kc * 8;
      } else {
        int gm = bm + row;
        av = gm < M;
        aoff = (size_t)gm * K + k0 + kc * 8;
      }
      sAh[e] = av ? *(const short8v*)(Ah + aoff) : ZV;
      sAl[e] = av ? *(const short8v*)(Al + aoff) : ZV;
      int gn = bn + row;
      bool bv = gn < N;
      size_t boff = (size_t)gn * ldb + (CONV ? tap * 768 : 0) + k0 + kc * 8;
      sBh[e] = bv ? *(const short8v*)(Bh + boff) : ZV;
      sBl[e] = bv ? *(const short8v*)(Bl + boff) : ZV;
    }
  };

  auto lds_write = [&]() {
    #pragma unroll
    for (int e = 0; e < 4; e++) {
      int row = s_row[e];
      int off = row * 64 + ((s_kc[e] ^ (row & 7)) * 8);   // XOR swizzle: conflict-free b128 read
      *(short8v*)(AsH + off) = sAh[e];
      *(short8v*)(AsL + off) = sAl[e];
      *(short8v*)(BsH + off) = sBh[e];
      *(short8v*)(BsL + off) = sBl[e];
    }
  };

  ffrag acc[4][4];
  const ffrag FZ = {0.f, 0.f, 0.f, 0.f};
  #pragma unroll
  for (int i = 0; i < 4; i++)
    #pragma unroll
    for (int j = 0; j < 4; j++) acc[i][j] = FZ;

  auto compute = [&]() {
    #pragma unroll
    for (int ks = 0; ks < 2; ks++) {
      short8v ahf[4], alf[4], bhf[4], blf[4];
      #pragma unroll
      for (int i = 0; i < 4; i++) {
        int ra = wm + i * 16 + lm;
        int oa = ra * 64 + (((lk + 4 * ks) ^ (ra & 7)) * 8);
        ahf[i] = *(const short8v*)(AsH + oa);
        alf[i] = *(const short8v*)(AsL + oa);
        int rb = wn + i * 16 + lm;
        int ob = rb * 64 + (((lk + 4 * ks) ^ (rb & 7)) * 8);
        bhf[i] = *(const short8v*)(BsH + ob);
        blf[i] = *(const short8v*)(BsL + ob);
      }
      #pragma unroll
      for (int i = 0; i < 4; i++)
        #pragma unroll
        for (int j = 0; j < 4; j++) {
          mfma_bf16(acc[i][j], ahf[i], bhf[j]);   // hi*hi
          mfma_bf16(acc[i][j], ahf[i], blf[j]);   // hi*lo
          mfma_bf16(acc[i][j], alf[i], bhf[j]);   // lo*hi
        }
    }
  };

  stage(0);
  lds_write();
  __syncthreads();
  for (int step = 0; step < nsteps; ++step) {
    bool more = step + 1 < nsteps;
    if (more) stage(step + 1);       // global loads in flight under compute
    compute();
    __syncthreads();
    if (more) { lds_write(); __syncthreads(); }
  }

  // C/D layout: col = lane&15, row = (lane>>4)*4 + reg  [m89-verified]
  #pragma unroll
  for (int i = 0; i < 4; i++) {
    #pragma unroll
    for (int r = 0; r < 4; r++) {
      int row = bm + wm + i * 16 + lk * 4 + r;
      if (row >= M) continue;
      #pragma unroll
      for (int j = 0; j < 4; j++) {
        int col = bn + wn + j * 16 + lm;
        if (col < N) Cout[(size_t)row * N + col] = acc[i][j][r];
      }
    }
  }
}

// sum 4 conv partials + bias into dst
__global__ void conv_reduce_kernel(float* __restrict__ dst, const float* __restrict__ part,
                                   const float* __restrict__ bias) {
  for (int gid = blockIdx.x * blockDim.x + threadIdx.x; gid < IMG * D_MODEL;
       gid += gridDim.x * blockDim.x) {
    float s = dst[gid] + bias[gid % D_MODEL];
    #pragma unroll
    for (int p = 0; p < 4; p++) s += part[(size_t)p * IMG * D_MODEL + gid];
    dst[gid] = s;
  }
}

// ---------------- conv1d (depthwise causal k=4) + silu ----------------
__global__ void conv1d_kernel(const float* __restrict__ zx, const float* __restrict__ cw,
                              const float* __restrict__ cb, float* __restrict__ xBC) {
  for (int gid = blockIdx.x * blockDim.x + threadIdx.x; gid < TLEN * CONV_DIM;
       gid += gridDim.x * blockDim.x) {
    int t = gid / CONV_DIM, ch = gid % CONV_DIM;
    float acc = cb[ch];
    #pragma unroll
    for (int k = 0; k < 4; k++) {
      int tt = t - 3 + k;
      if (tt >= 0) acc += zx[(size_t)tt * DPROJ + DIN + ch] * cw[ch * 4 + k];
    }
    xBC[gid] = siluf(acc);
  }
}

__global__ void dt_kernel(const float* __restrict__ zx, const float* __restrict__ dt_bias,
                          float* __restrict__ dt) {
  for (int gid = blockIdx.x * blockDim.x + threadIdx.x; gid < TLEN * NH;
       gid += gridDim.x * blockDim.x) {
    int t = gid / NH, h = gid % NH;
    float v = zx[(size_t)t * DPROJ + DPROJ - NH + h] + dt_bias[h];
    dt[gid] = softplusf(v);
  }
}

// ---------------- A cumsum per chunk/head ----------------
__global__ void acs_kernel(const float* __restrict__ dt, const float* __restrict__ A_log,
                           float* __restrict__ Acs, float* __restrict__ csum) {
  int gid = blockIdx.x * blockDim.x + threadIdx.x;
  if (gid >= NCHUNK * NH) return;
  int c = gid / NH, h = gid % NH;
  float A = -expf(A_log[h]);
  float acc = 0.f;
  for (int l = 0; l < CHUNK; l++) {
    int t = c * CHUNK + l;
    float a = (t < TLEN) ? dt[(size_t)t * NH + h] * A : 0.f;
    acc += a;
    Acs[(size_t)(c * CHUNK + l) * NH + h] = acc;
  }
  csum[c * NH + h] = acc;
}

// ---------------- per-chunk state: cstate[c][h][p][n] ----------------
__global__ __launch_bounds__(256) void chunk_state_kernel(const float* __restrict__ xBC,
                                                          const float* __restrict__ dt,
                                                          const float* __restrict__ Acs,
                                                          const float* __restrict__ csum,
                                                          float* __restrict__ cstate) {
  int c = blockIdx.x, h = blockIdx.y;
  __shared__ float Bs[CHUNK][NSTATE];
  __shared__ float Xs[CHUNK][HP];
  int tid = threadIdx.x;
  float cs = csum[c * NH + h];
  for (int idx = tid; idx < CHUNK * 64; idx += 256) {
    int l = idx >> 6, n = idx & 63;
    int t = c * CHUNK + l;
    if (t < TLEN) {
      float a = Acs[(size_t)t * NH + h];
      Bs[l][n] = xBC[(size_t)t * CONV_DIM + DIN + n];
      Xs[l][n] = xBC[(size_t)t * CONV_DIM + h * HP + n] * dt[(size_t)t * NH + h] * expf(cs - a);
    } else { Bs[l][n] = 0.f; Xs[l][n] = 0.f; }
  }
  __syncthreads();
  int pt = (tid >> 4) * 4, nt = (tid & 15) * 4;
  float acc[4][4] = {};
  for (int l = 0; l < CHUNK; l++) {
    float xv[4], bv[4];
    #pragma unroll
    for (int i = 0; i < 4; i++) xv[i] = Xs[l][pt + i];
    #pragma unroll
    for (int j = 0; j < 4; j++) bv[j] = Bs[l][nt + j];
    #pragma unroll
    for (int i = 0; i < 4; i++)
      #pragma unroll
      for (int j = 0; j < 4; j++) acc[i][j] += xv[i] * bv[j];
  }
  size_t base = (((size_t)c * NH) + h) * 64 * 64;
  for (int i = 0; i < 4; i++)
    for (int j = 0; j < 4; j++)
      cstate[base + (size_t)(pt + i) * 64 + nt + j] = acc[i][j];
}

// ---------------- sequential inter-chunk scan ----------------
__global__ __launch_bounds__(256) void state_scan_kernel(const float* __restrict__ cstate,
                                                         const float* __restrict__ csum,
                                                         float* __restrict__ sstate) {
  int h = blockIdx.x;
  int tid = threadIdx.x;
  float S[16];
  #pragma unroll
  for (int j = 0; j < 16; j++) S[j] = 0.f;
  for (int z = 0; z < NCHUNK; z++) {
    size_t base = (((size_t)z * NH) + h) * 4096;
    float dec = expf(csum[z * NH + h]);
    #pragma unroll
    for (int j = 0; j < 16; j++) {
      int idx = j * 256 + tid;
      sstate[base + idx] = S[j];
      S[j] = S[j] * dec + cstate[base + idx];
    }
  }
}

// ---------------- SSD output Y = Yd + Yo + Dp*xh ----------------
__global__ __launch_bounds__(256, 1) void ssd_y_kernel(const float* __restrict__ xBC,
                                                       const float* __restrict__ dt,
                                                       const float* __restrict__ Acs,
                                                       const float* __restrict__ sstate,
                                                       const float* __restrict__ Dp,
                                                       float* __restrict__ y) {
  int c = blockIdx.x, h = blockIdx.y;
  __shared__ float Cs[CHUNK][NSTATE];
  __shared__ float Bx[CHUNK][NSTATE];
  __shared__ float Gm[CHUNK][CHUNK];
  __shared__ float Ash[CHUNK];
  int tid = threadIdx.x;
  for (int idx = tid; idx < CHUNK * 64; idx += 256) {
    int l = idx >> 6, n = idx & 63;
    int t = c * CHUNK + l;
    bool v = t < TLEN;
    Cs[l][n] = v ? xBC[(size_t)t * CONV_DIM + DIN + NSTATE + n] : 0.f;
    Bx[l][n] = v ? xBC[(size_t)t * CONV_DIM + DIN + n] : 0.f;
  }
  if (tid < CHUNK) Ash[tid] = Acs[(size_t)(c * CHUNK + tid) * NH + h];
  __syncthreads();
  {
    int lt = (tid >> 4) * 8, st = (tid & 15) * 8;
    float acc[8][8] = {};
    for (int n = 0; n < 64; n++) {
      float cv[8], bv[8];
      #pragma unroll
      for (int i = 0; i < 8; i++) cv[i] = Cs[lt + i][n];
      #pragma unroll
      for (int j = 0; j < 8; j++) bv[j] = Bx[st + j][n];
      #pragma unroll
      for (int i = 0; i < 8; i++)
        #pragma unroll
        for (int j = 0; j < 8; j++) acc[i][j] += cv[i] * bv[j];
    }
    for (int i = 0; i < 8; i++)
      for (int j = 0; j < 8; j++) {
        int l = lt + i, s = st + j;
        Gm[l][s] = (s <= l) ? acc[i][j] * expf(Ash[l] - Ash[s]) : 0.f;
      }
  }
  __syncthreads();
  for (int idx = tid; idx < CHUNK * 64; idx += 256) {
    int l = idx >> 6, p = idx & 63;
    int t = c * CHUNK + l;
    Bx[l][p] = (t < TLEN) ? xBC[(size_t)t * CONV_DIM + h * HP + p] * dt[(size_t)t * NH + h] : 0.f;
  }
  __syncthreads();
  int lt = (tid >> 4) * 8, pt = (tid & 15) * 4;
  float yd[8][4] = {};
  for (int s = 0; s < CHUNK; s++) {
    float m8[8], x4[4];
    #pragma unroll
    for (int i = 0; i < 8; i++) m8[i] = Gm[lt + i][s];
    #pragma unroll
    for (int j = 0; j < 4; j++) x4[j] = Bx[s][pt + j];
    #pragma unroll
    for (int i = 0; i < 8; i++)
      #pragma unroll
      for (int j = 0; j < 4; j++) yd[i][j] += m8[i] * x4[j];
  }
  __syncthreads();
  for (int idx = tid; idx < 64 * 64; idx += 256) {
    int p = idx >> 6, n = idx & 63;
    Bx[p][n] = sstate[(((size_t)c * NH) + h) * 4096 + idx];
  }
  __syncthreads();
  float yo[8][4] = {};
  for (int n = 0; n < 64; n++) {
    float c8[8], s4[4];
    #pragma unroll
    for (int i = 0; i < 8; i++) c8[i] = Cs[lt + i][n];
    #pragma unroll
    for (int j = 0; j < 4; j++) s4[j] = Bx[pt + j][n];
    #pragma unroll
    for (int i = 0; i < 8; i++)
      #pragma unroll
      for (int j = 0; j < 4; j++) yo[i][j] += c8[i] * s4[j];
  }
  float dph = Dp[h];
  for (int i = 0; i < 8; i++) {
    int l = lt + i, t = c * CHUNK + l;
    if (t >= TLEN) continue;
    float ea = expf(Ash[l]);
    for (int j = 0; j < 4; j++) {
      int p = pt + j;
      float xh = xBC[(size_t)t * CONV_DIM + h * HP + p];
      y[(size_t)t * DIN + h * HP + p] = yd[i][j] + ea * yo[i][j] + dph * xh;
    }
  }
}

// ---------------- gate (silu(z)) + RMS norm over 1536 -> split bf16 ----------------
__global__ __launch_bounds__(256) void gate_rms_kernel(const float* __restrict__ y,
                                                       const float* __restrict__ zx,
                                                       const float* __restrict__ rms_w,
                                                       short* __restrict__ oh,
                                                       short* __restrict__ ol) {
  int t = blockIdx.x;
  if (t >= TLEN) return;
  __shared__ float red[256];
  int tid = threadIdx.x;
  float v[6];
  float ss = 0.f;
  #pragma unroll
  for (int e = 0; e < 6; e++) {
    int d = e * 256 + tid;
    float z = zx[(size_t)t * DPROJ + d];
    float val = y[(size_t)t * DIN + d] * siluf(z);
    v[e] = val;
    ss += val * val;
  }
  red[tid] = ss;
  __syncthreads();
  for (int o = 128; o; o >>= 1) { if (tid < o) red[tid] += red[tid + o]; __syncthreads(); }
  float scale = rsqrtf(red[0] / (float)DIN + 1e-5f);
  #pragma unroll
  for (int e = 0; e < 6; e++) {
    int d = e * 256 + tid;
    short h, l;
    splitf(v[e] * scale * rms_w[d], h, l);
    oh[(size_t)t * DIN + d] = h;
    ol[(size_t)t * DIN + d] = l;
  }
}

// ---------------- residual add + image flip ----------------
__global__ void resadd_flip_kernel(const float* __restrict__ x, const float* __restrict__ hbuf,
                                   float* __restrict__ xnew) {
  for (int gid = blockIdx.x * blockDim.x + threadIdx.x; gid < TLEN * D_MODEL;
       gid += gridDim.x * blockDim.x) {
    int t = gid / D_MODEL, d = gid % D_MODEL;
    int st = (t < 65) ? t : 65 + (IMG - 1 - (t - 65));
    size_t sidx = (size_t)st * D_MODEL + d;
    xnew[gid] = x[sidx] + hbuf[sidx];
  }
}

// ---------------- head: y_hat + loss ----------------
__global__ void zero_loss_kernel(float* loss) { *loss = 0.f; }

__global__ void head_kernel(const float* __restrict__ ximg, const float* __restrict__ w,
                            const float* __restrict__ b, const float* __restrict__ im64,
                            float* __restrict__ out, float* __restrict__ loss_acc) {
  int p = blockIdx.x;
  int lane = threadIdx.x;
  const float* row = ximg + (size_t)p * D_MODEL;
  float a0 = 0.f, a1 = 0.f, a2 = 0.f;
  for (int d = lane; d < D_MODEL; d += 64) {
    float xv = row[d];
    a0 += xv * w[d];
    a1 += xv * w[D_MODEL + d];
    a2 += xv * w[2 * D_MODEL + d];
  }
  for (int off = 32; off; off >>= 1) {
    a0 += __shfl_down(a0, off);
    a1 += __shfl_down(a1, off);
    a2 += __shfl_down(a2, off);
  }
  if (lane == 0) {
    a0 += b[0]; a1 += b[1]; a2 += b[2];
    out[p * 3 + 0] = a0;
    out[p * 3 + 1] = a1;
    out[p * 3 + 2] = a2;
    float e0 = a0 - im64[p * 3 + 0];
    float e1 = a1 - im64[p * 3 + 1];
    float e2 = a2 - im64[p * 3 + 2];
    atomicAdd(loss_acc, e0 * e0 + e1 * e1 + e2 * e2);
  }
}

__global__ void finalize_loss_kernel(const float* __restrict__ loss_acc, float* __restrict__ out) {
  out[IMG * 3] = loss_acc[0] / (float)(IMG * 3);
}

extern "C" void kernel_launch(void* const* d_in, const int* in_sizes, int n_in,
                              void* d_out, int out_size, void* d_ws, size_t ws_size,
                              hipStream_t stream) {
  const float* im8       = (const float*)d_in[0];
  const float* im64      = (const float*)d_in[1];
  const float* from_rgb_w= (const float*)d_in[2];
  const float* from_rgb_b= (const float*)d_in[3];
  const float* to_rgb_w  = (const float*)d_in[4];
  const float* to_rgb_b  = (const float*)d_in[5];
  const float* s0        = (const float*)d_in[6];
  const float* suffix    = (const float*)d_in[7];
  const float* norm0_w   = (const float*)d_in[8];
  const float* norm0_b   = (const float*)d_in[9];
  const float* in_proj_w = (const float*)d_in[10];
  const float* conv1d_w  = (const float*)d_in[11];
  const float* conv1d_b  = (const float*)d_in[12];
  const float* dt_bias   = (const float*)d_in[13];
  const float* A_log     = (const float*)d_in[14];
  const float* Dp        = (const float*)d_in[15];
  const float* rms_w     = (const float*)d_in[16];
  const float* out_proj_w= (const float*)d_in[17];
  const float* ln_w      = (const float*)d_in[18];
  const float* ln_b      = (const float*)d_in[19];
  const float* lnc_w     = (const float*)d_in[20];
  const float* lnc_b     = (const float*)d_in[21];
  const float* conv2d_w  = (const float*)d_in[22];
  const float* conv2d_b  = (const float*)d_in[23];

  float* W = (float*)d_ws;
  size_t off = 0;
  auto alloc = [&](size_t n) { float* p = W + off; off += (n + 3) & ~(size_t)3; return p; };
  auto salloc = [&](size_t n) { return (short*)alloc((n + 1) / 2); };
  float* xA     = alloc((size_t)TLEN * D_MODEL);
  float* xB     = alloc((size_t)TLEN * D_MODEL);
  float* hbuf   = alloc((size_t)TLEN * D_MODEL);
  float* zx     = alloc((size_t)TLEN * DPROJ);   // reused as conv partial buffers (4*IMG*768 <= TLEN*DPROJ)
  float* xBC    = alloc((size_t)TLEN * CONV_DIM);
  float* dtb    = alloc((size_t)TLEN * NH);
  float* Acs    = alloc((size_t)TPAD * NH);
  float* csum   = alloc((size_t)NCHUNK * NH);
  float* ybuf   = alloc((size_t)TLEN * DIN);
  float* cstate = alloc((size_t)NCHUNK * NH * 64 * 64);
  float* sstate = alloc((size_t)NCHUNK * NH * 64 * 64);
  float* e8     = alloc((size_t)64 * D_MODEL);
  float* lossp  = alloc(4);
  short* xs_h   = salloc((size_t)TLEN * D_MODEL);
  short* xs_l   = salloc((size_t)TLEN * D_MODEL);
  short* ybs_h  = salloc((size_t)TLEN * DIN);
  short* ybs_l  = salloc((size_t)TLEN * DIN);
  short* img_h  = salloc((size_t)IMG * D_MODEL);
  short* img_l  = salloc((size_t)IMG * D_MODEL);
  short* wA_h   = salloc((size_t)DPROJ * D_MODEL);
  short* wA_l   = salloc((size_t)DPROJ * D_MODEL);
  short* wO_h   = salloc((size_t)D_MODEL * DIN);
  short* wO_l   = salloc((size_t)D_MODEL * DIN);
  // split conv weights ALIAS the xBC..cstate region (14.75 Mf needed, 16.76 Mf available,
  // stops before sstate). All aliased buffers are dead after ssd_y/gate_rms; split_convw
  // runs after gate_rms; everything aliased is re-written next wrap before any read.
  short* wC_h   = (short*)xBC;
  short* wC_l   = wC_h + (size_t)D_MODEL * KCONV;
  (void)ws_size; (void)in_sizes; (void)n_in; (void)out_size;

  float* outp = (float*)d_out;

  e8_kernel<<<(64 * D_MODEL + 255) / 256, 256, 0, stream>>>(im8, from_rgb_w, from_rgb_b, e8);
  build_x_kernel<<<2048, 256, 0, stream>>>(e8, s0, suffix, xB);
  ln_kernel<<<TLEN, 256, 0, stream>>>(xB, norm0_w, norm0_b, xA, nullptr, nullptr, TLEN);

  float* x = xA;
  float* xn = xB;
  for (int i = 0; i < 8; i++) {
    const float* ipw = in_proj_w + (size_t)i * DPROJ * D_MODEL;
    const float* cw  = conv1d_w + (size_t)i * CONV_DIM * 4;
    const float* cb  = conv1d_b + (size_t)i * CONV_DIM;
    const float* dtbias_i = dt_bias + (size_t)i * NH;
    const float* alog_i   = A_log + (size_t)i * NH;
    const float* dp_i     = Dp + (size_t)i * NH;
    const float* rmsw_i   = rms_w + (size_t)i * DIN;
    const float* opw      = out_proj_w + (size_t)i * D_MODEL * DIN;
    const float* lnw_i    = ln_w + (size_t)i * D_MODEL;
    const float* lnb_i    = ln_b + (size_t)i * D_MODEL;
    const float* lncw_i   = lnc_w + (size_t)i * D_MODEL;
    const float* lncb_i   = lnc_b + (size_t)i * D_MODEL;
    const float* c2w      = conv2d_w + (size_t)i * 25 * D_MODEL * D_MODEL;
    const float* c2b      = conv2d_b + (size_t)i * D_MODEL;

    split_mat_kernel<<<1024, 256, 0, stream>>>(ipw, wA_h, wA_l, DPROJ * D_MODEL);
    split_mat_kernel<<<1024, 256, 0, stream>>>(opw, wO_h, wO_l, D_MODEL * DIN);

    ln_kernel<<<TLEN, 256, 0, stream>>>(x, lnw_i, lnb_i, nullptr, xs_h, xs_l, TLEN);
    mm_bf16<0><<<dim3(33, 26), 256, 0, stream>>>(xs_h, xs_l, wA_h, wA_l, zx, nullptr,
                                                 TLEN, DPROJ, D_MODEL, D_MODEL);
    conv1d_kernel<<<4096, 256, 0, stream>>>(zx, cw, cb, xBC);
    dt_kernel<<<(TLEN * NH + 255) / 256, 256, 0, stream>>>(zx, dtbias_i, dtb);
    acs_kernel<<<(NCHUNK * NH + 255) / 256, 256, 0, stream>>>(dtb, alog_i, Acs, csum);
    chunk_state_kernel<<<dim3(NCHUNK, NH), 256, 0, stream>>>(xBC, dtb, Acs, csum, cstate);
    state_scan_kernel<<<NH, 256, 0, stream>>>(cstate, csum, sstate);
    ssd_y_kernel<<<dim3(NCHUNK, NH), 256, 0, stream>>>(xBC, dtb, Acs, sstate, dp_i, ybuf);
    gate_rms_kernel<<<TLEN, 256, 0, stream>>>(ybuf, zx, rmsw_i, ybs_h, ybs_l);
    // conv weight split AFTER gate_rms: wC aliases xBC/dtb/Acs/csum/ybuf/(part of cstate),
    // all dead at this point in the wrap.
    split_convw_kernel<<<dim3(25, 24, 24), 256, 0, stream>>>(c2w, wC_h, wC_l);
    mm_bf16<0><<<dim3(33, 6), 256, 0, stream>>>(ybs_h, ybs_l, wO_h, wO_l, hbuf, nullptr,
                                                TLEN, D_MODEL, DIN, DIN);
    ln_kernel<<<IMG, 256, 0, stream>>>(hbuf + (size_t)65 * D_MODEL, lncw_i, lncb_i,
                                       nullptr, img_h, img_l, IMG);
    // conv2d as implicit GEMM, 5-tap groups over grid.z; partials into zx (dead here)
    mm_bf16<1><<<dim3(32, 6, 5), 256, 0, stream>>>(img_h, img_l, wC_h, wC_l,
                                                   hbuf + (size_t)65 * D_MODEL, zx,
                                                   IMG, D_MODEL, 768, KCONV);
    conv_reduce_kernel<<<2048, 256, 0, stream>>>(hbuf + (size_t)65 * D_MODEL, zx, c2b);
    resadd_flip_kernel<<<2048, 256, 0, stream>>>(x, hbuf, xn);
    float* tmp = x; x = xn; xn = tmp;
  }

  zero_loss_kernel<<<1, 1, 0, stream>>>(lossp);
  head_kernel<<<IMG, 64, 0, stream>>>(x + (size_t)65 * D_MODEL, to_rgb_w, to_rgb_b, im64,
                                      outp, lossp);
  finalize_loss_kernel<<<1, 1, 0, stream>>>(lossp, outp);
}